// Round 1
// baseline (2663.210 us; speedup 1.0000x reference)
//
#include <hip/hip_runtime.h>
#include <math.h>

// ---------------------------------------------------------------------------
// GIN multi-graph model, MI355X (gfx950)
// Strategy:
//   - Build CSR (by dst) once per call: histogram + scan + scatter (int atomics)
//   - Per layer: fused wave-per-node kernel:
//       gather (coalesced 256B row reads) -> GEMM1(64x64) -> BN -> ReLU
//       -> GEMM2(64x64) -> ReLU -> write x_out
//     GEMMs keep W1/W2 in VGPRs (64+64 regs/lane) and broadcast the input
//     vector via v_readlane (VALU), so LDS is untouched.
//   - Pooling: deterministic segmented sum per graph (batch is sorted).
//   - FC head: wave-per-graph, feat in LDS, 448x64 + 64x2 + sigmoid.
// ---------------------------------------------------------------------------

static __device__ __forceinline__ float bcast_lane(float v, int k) {
    return __int_as_float(__builtin_amdgcn_readlane(__float_as_int(v), k));
}

// ---------------- CSR build ----------------

__global__ void k_hist(const int* __restrict__ dst, int* __restrict__ deg, int E) {
    int i = blockIdx.x * blockDim.x + threadIdx.x;
    int stride = gridDim.x * blockDim.x;
    for (; i < E; i += stride) atomicAdd(&deg[dst[i]], 1);
}

#define SCAN_B 512

__global__ void k_scan1(const int* __restrict__ deg, int* __restrict__ ex,
                        int* __restrict__ bsum, int n) {
    __shared__ int s[SCAN_B];
    int t = threadIdx.x;
    int i = blockIdx.x * SCAN_B + t;
    int v = (i < n) ? deg[i] : 0;
    s[t] = v;
    __syncthreads();
    for (int off = 1; off < SCAN_B; off <<= 1) {
        int tv = (t >= off) ? s[t - off] : 0;
        __syncthreads();
        s[t] += tv;
        __syncthreads();
    }
    if (i < n) ex[i] = s[t] - v;             // exclusive within block
    if (t == SCAN_B - 1) bsum[blockIdx.x] = s[t];
}

__global__ void k_scan2(int* __restrict__ bsum, int nb) {
    __shared__ int s[SCAN_B];
    int t = threadIdx.x;
    int v = (t < nb) ? bsum[t] : 0;
    s[t] = v;
    __syncthreads();
    for (int off = 1; off < SCAN_B; off <<= 1) {
        int tv = (t >= off) ? s[t - off] : 0;
        __syncthreads();
        s[t] += tv;
        __syncthreads();
    }
    if (t < nb) bsum[t] = s[t] - v;          // exclusive block offsets
}

__global__ void k_scan3(int* __restrict__ ex, const int* __restrict__ bsum,
                        int n, int E) {
    int i = blockIdx.x * SCAN_B + threadIdx.x;
    if (i < n) ex[i] += bsum[blockIdx.x];
    if (blockIdx.x == 0 && threadIdx.x == 0) ex[n] = E;
}

__global__ void k_scatter(const int* __restrict__ src, const int* __restrict__ dst,
                          const int* __restrict__ row_start, int* __restrict__ cur,
                          int* __restrict__ csr, int E) {
    int i = blockIdx.x * blockDim.x + threadIdx.x;
    int stride = gridDim.x * blockDim.x;
    for (; i < E; i += stride) {
        int d = dst[i];
        int p = atomicAdd(&cur[d], 1);
        csr[row_start[d] + p] = src[i];
    }
}

// graph start offsets via binary search over sorted batch
__global__ void k_gstart(const int* __restrict__ batch, int* __restrict__ gs,
                         int n, int G) {
    int g = blockIdx.x * blockDim.x + threadIdx.x;
    if (g > G) return;
    if (g == G) { gs[G] = n; return; }
    int lo = 0, hi = n;
    while (lo < hi) {
        int mid = (lo + hi) >> 1;
        if (batch[mid] < g) lo = mid + 1; else hi = mid;
    }
    gs[g] = lo;
}

// ---------------- fused GIN layer ----------------

__global__ __launch_bounds__(256) void k_layer(
    const float* __restrict__ x, const int* __restrict__ row_start,
    const int* __restrict__ csr_src,
    const float* __restrict__ W1, const float* __restrict__ b1,
    const float* __restrict__ gamma, const float* __restrict__ beta,
    const float* __restrict__ mean, const float* __restrict__ var,
    const float* __restrict__ W2, const float* __restrict__ b2,
    float* __restrict__ xout, int n)
{
    int lane = threadIdx.x & 63;
    int wid = (blockIdx.x * blockDim.x + threadIdx.x) >> 6;
    int nwaves = (gridDim.x * blockDim.x) >> 6;

    // per-lane column of W1/W2 held in registers (64+64 VGPRs)
    float w1[64], w2[64];
#pragma unroll
    for (int k = 0; k < 64; ++k) w1[k] = W1[k * 64 + lane];
#pragma unroll
    for (int k = 0; k < 64; ++k) w2[k] = W2[k * 64 + lane];
    float bias1 = b1[lane];
    float sc = gamma[lane] * rsqrtf(var[lane] + 1e-5f);
    float sh = beta[lane] - mean[lane] * sc;
    float bias2 = b2[lane];

    for (int node = wid; node < n; node += nwaves) {
        // GIN aggregation: x[node] + sum of neighbors (CSR by dst)
        float acc = x[(size_t)node * 64 + lane];
        int s0 = row_start[node];
        int s1 = row_start[node + 1];
        for (int j = s0; j < s1; ++j) {
            int srcn = csr_src[j];                 // wave-uniform
            acc += x[(size_t)srcn * 64 + lane];    // coalesced 256B row
        }
        // GEMM1: h[d] = b1[d] + sum_k acc[k] * W1[k][d]
        float h = bias1;
#pragma unroll
        for (int k = 0; k < 64; ++k) h += bcast_lane(acc, k) * w1[k];
        // BatchNorm (eval) + ReLU
        h = h * sc + sh;
        h = fmaxf(h, 0.0f);
        // GEMM2 + ReLU
        float o = bias2;
#pragma unroll
        for (int k = 0; k < 64; ++k) o += bcast_lane(h, k) * w2[k];
        o = fmaxf(o, 0.0f);
        xout[(size_t)node * 64 + lane] = o;
    }
}

// ---------------- per-graph pooling (segmented sum) ----------------

__global__ __launch_bounds__(256) void k_pool(const float* __restrict__ x,
                                              const int* __restrict__ gs,
                                              float* __restrict__ pooled,
                                              int G, int l) {
    int lane = threadIdx.x & 63;
    int wid = (blockIdx.x * blockDim.x + threadIdx.x) >> 6;
    if (wid >= G) return;
    int s0 = gs[wid], s1 = gs[wid + 1];
    float s = 0.0f;
    for (int nd = s0; nd < s1; ++nd) s += x[(size_t)nd * 64 + lane];
    pooled[(size_t)wid * 192 + l * 64 + lane] = s;
}

// ---------------- FC head ----------------

__global__ __launch_bounds__(256) void k_fc(
    const float* __restrict__ pooled, const int* __restrict__ acid,
    const float* __restrict__ conc, const float* __restrict__ emb_acid,
    const float* __restrict__ emb_conc, const float* __restrict__ fc1W,
    const float* __restrict__ fc1b, const float* __restrict__ fc2W,
    const float* __restrict__ fc2b, float* __restrict__ out, int G)
{
    __shared__ float sf[4][448];
    int lane = threadIdx.x & 63;
    int w = threadIdx.x >> 6;
    int g = blockIdx.x * 4 + w;
    if (g < G) {
        const float* pr = pooled + (size_t)g * 192;
        sf[w][lane] = pr[lane];
        sf[w][lane + 64] = pr[lane + 64];
        sf[w][lane + 128] = pr[lane + 128];
        const float* ea = emb_acid + acid[g] * 128;
        int ci = (conc[g] == 0.5f) ? 0 : 1;
        const float* ec = emb_conc + ci * 128;
        sf[w][192 + lane] = ea[lane];
        sf[w][256 + lane] = ea[lane + 64];
        sf[w][320 + lane] = ec[lane];
        sf[w][384 + lane] = ec[lane + 64];
    }
    __syncthreads();
    if (g >= G) return;
    float h = fc1b[lane];
    for (int k = 0; k < 448; ++k) h += sf[w][k] * fc1W[k * 64 + lane];
    h = fmaxf(h, 0.0f);
    float p0 = h * fc2W[lane * 2 + 0];
    float p1 = h * fc2W[lane * 2 + 1];
    for (int off = 32; off; off >>= 1) {
        p0 += __shfl_xor(p0, off, 64);
        p1 += __shfl_xor(p1, off, 64);
    }
    if (lane == 0) {
        out[g * 2 + 0] = 1.0f / (1.0f + expf(-(p0 + fc2b[0])));
        out[g * 2 + 1] = 1.0f / (1.0f + expf(-(p1 + fc2b[1])));
    }
}

// ---------------- launch ----------------

extern "C" void kernel_launch(void* const* d_in, const int* in_sizes, int n_in,
                              void* d_out, int out_size, void* d_ws, size_t ws_size,
                              hipStream_t stream)
{
    const float* x_a      = (const float*)d_in[0];
    const int*   ei       = (const int*)d_in[1];
    const int*   batch    = (const int*)d_in[2];
    const int*   acid     = (const int*)d_in[3];
    const float* conc     = (const float*)d_in[4];
    // d_in[5] = num_graphs (scalar), use in_sizes[3] instead
    const float* W1s      = (const float*)d_in[6];
    const float* b1s      = (const float*)d_in[7];
    const float* gammas   = (const float*)d_in[8];
    const float* betas    = (const float*)d_in[9];
    const float* bn_means = (const float*)d_in[10];
    const float* bn_vars  = (const float*)d_in[11];
    const float* W2s      = (const float*)d_in[12];
    const float* b2s      = (const float*)d_in[13];
    const float* emb_acid = (const float*)d_in[14];
    const float* emb_conc = (const float*)d_in[15];
    const float* fc1W     = (const float*)d_in[16];
    const float* fc1b     = (const float*)d_in[17];
    const float* fc2W     = (const float*)d_in[18];
    const float* fc2b     = (const float*)d_in[19];

    const int N = in_sizes[0] / 64;
    const int E = in_sizes[1] / 2;
    const int G = in_sizes[3];
    const int L = in_sizes[6] / (64 * 64);

    char* ws = (char*)d_ws;
    size_t off = 0;
    auto alloc = [&](size_t bytes) -> void* {
        void* p = ws + off;
        off += (bytes + 255) & ~(size_t)255;
        return p;
    };
    float* buf0      = (float*)alloc((size_t)N * 64 * 4);
    float* buf1      = (float*)alloc((size_t)N * 64 * 4);
    float* pooled    = (float*)alloc((size_t)G * 192 * 4);
    int*   row_start = (int*)alloc((size_t)(N + 1) * 4);
    int*   deg       = (int*)alloc((size_t)N * 4);      // reused as cursor
    int*   csr       = (int*)alloc((size_t)E * 4);
    int*   bsum      = (int*)alloc(4096);
    int*   gs        = (int*)alloc((size_t)(G + 1) * 4);

    const int* srcv = ei;
    const int* dstv = ei + E;

    // CSR build (once; reused by all 3 layers)
    hipMemsetAsync(deg, 0, (size_t)N * 4, stream);
    k_hist<<<1024, 256, 0, stream>>>(dstv, deg, E);
    int nb = (N + SCAN_B - 1) / SCAN_B;
    k_scan1<<<nb, SCAN_B, 0, stream>>>(deg, row_start, bsum, N);
    k_scan2<<<1, SCAN_B, 0, stream>>>(bsum, nb);
    k_scan3<<<nb, SCAN_B, 0, stream>>>(row_start, bsum, N, E);
    hipMemsetAsync(deg, 0, (size_t)N * 4, stream);
    k_scatter<<<1024, 256, 0, stream>>>(srcv, dstv, row_start, deg, csr, E);
    k_gstart<<<(G + 256) / 256, 256, 0, stream>>>(batch, gs, N, G);

    // GIN layers (ping-pong x between buf0/buf1)
    const float* xin = x_a;
    float* bufs[2] = {buf0, buf1};
    for (int l = 0; l < L; ++l) {
        float* xout = bufs[l & 1];
        k_layer<<<2048, 256, 0, stream>>>(
            xin, row_start, csr,
            W1s + (size_t)l * 64 * 64, b1s + l * 64,
            gammas + l * 64, betas + l * 64,
            bn_means + l * 64, bn_vars + l * 64,
            W2s + (size_t)l * 64 * 64, b2s + l * 64,
            xout, N);
        k_pool<<<(G + 3) / 4, 256, 0, stream>>>(xout, gs, pooled, G, l);
        xin = xout;
    }

    // FC head
    k_fc<<<(G + 3) / 4, 256, 0, stream>>>(pooled, acid, conc, emb_acid, emb_conc,
                                          fc1W, fc1b, fc2W, fc2b,
                                          (float*)d_out, G);
}

// Round 2
// 1184.877 us; speedup vs baseline: 2.2477x; 2.2477x over previous
//
#include <hip/hip_runtime.h>
#include <math.h>

// ---------------------------------------------------------------------------
// GIN multi-graph model, MI355X (gfx950) — round 2
// Split latency-bound gather from VALU-bound GEMM; force weights into VGPRs.
// ---------------------------------------------------------------------------

static __device__ __forceinline__ float rlf(float v, int k) {
    return __int_as_float(__builtin_amdgcn_readlane(__float_as_int(v), k));
}
static __device__ __forceinline__ int rli(int v, int k) {
    return __builtin_amdgcn_readlane(v, k);
}

// ---------------- CSR build ----------------

__global__ void k_hist(const int* __restrict__ dst, int* __restrict__ deg, int E) {
    int i = blockIdx.x * blockDim.x + threadIdx.x;
    int stride = gridDim.x * blockDim.x;
    for (; i < E; i += stride) atomicAdd(&deg[dst[i]], 1);
}

#define SCAN_B 512

__global__ void k_scan1(const int* __restrict__ deg, int* __restrict__ ex,
                        int* __restrict__ bsum, int n) {
    __shared__ int s[SCAN_B];
    int t = threadIdx.x;
    int i = blockIdx.x * SCAN_B + t;
    int v = (i < n) ? deg[i] : 0;
    s[t] = v;
    __syncthreads();
    for (int off = 1; off < SCAN_B; off <<= 1) {
        int tv = (t >= off) ? s[t - off] : 0;
        __syncthreads();
        s[t] += tv;
        __syncthreads();
    }
    if (i < n) ex[i] = s[t] - v;
    if (t == SCAN_B - 1) bsum[blockIdx.x] = s[t];
}

__global__ void k_scan2(int* __restrict__ bsum, int nb) {
    __shared__ int s[SCAN_B];
    int t = threadIdx.x;
    int v = (t < nb) ? bsum[t] : 0;
    s[t] = v;
    __syncthreads();
    for (int off = 1; off < SCAN_B; off <<= 1) {
        int tv = (t >= off) ? s[t - off] : 0;
        __syncthreads();
        s[t] += tv;
        __syncthreads();
    }
    if (t < nb) bsum[t] = s[t] - v;
}

__global__ void k_scan3(int* __restrict__ ex, const int* __restrict__ bsum,
                        int n, int E) {
    int i = blockIdx.x * SCAN_B + threadIdx.x;
    if (i < n) ex[i] += bsum[blockIdx.x];
    if (blockIdx.x == 0 && threadIdx.x == 0) ex[n] = E;
}

__global__ void k_scatter(const int* __restrict__ src, const int* __restrict__ dst,
                          const int* __restrict__ row_start, int* __restrict__ cur,
                          int* __restrict__ csr, int E) {
    int i = blockIdx.x * blockDim.x + threadIdx.x;
    int stride = gridDim.x * blockDim.x;
    for (; i < E; i += stride) {
        int d = dst[i];
        int p = atomicAdd(&cur[d], 1);
        csr[row_start[d] + p] = src[i];
    }
}

__global__ void k_gstart(const int* __restrict__ batch, int* __restrict__ gs,
                         int n, int G) {
    int g = blockIdx.x * blockDim.x + threadIdx.x;
    if (g > G) return;
    if (g == G) { gs[G] = n; return; }
    int lo = 0, hi = n;
    while (lo < hi) {
        int mid = (lo + hi) >> 1;
        if (batch[mid] < g) lo = mid + 1; else hi = mid;
    }
    gs[g] = lo;
}

// weight transpose: Wt[l][j][k] = W[l][k][j]  (lane j reads contiguous row)
__global__ void k_wt(const float* __restrict__ W, float* __restrict__ Wt, int total) {
    int i = blockIdx.x * blockDim.x + threadIdx.x;
    if (i >= total) return;
    int l = i >> 12, r = i & 4095, j = r >> 6, k = r & 63;
    Wt[(l << 12) + (j << 6) + k] = W[(l << 12) + (k << 6) + j];
}

// ---------------- gather: agg[n] = x[n] + sum_{j in CSR row n} x[j] ----------

__global__ __launch_bounds__(256) void k_gather(
    const float* __restrict__ x, const int* __restrict__ row_start,
    const int* __restrict__ csr, float* __restrict__ agg, int n)
{
    int lane = threadIdx.x & 63;
    int wid = (blockIdx.x * blockDim.x + threadIdx.x) >> 6;
    int nw = (gridDim.x * blockDim.x) >> 6;
    for (int node = wid; node < n; node += nw) {
        float acc = x[(size_t)node * 64 + lane];
        int s0 = row_start[node], s1 = row_start[node + 1];
        for (int base = s0; base < s1; base += 64) {
            int cnt = min(64, s1 - base);
            // all (<=64) neighbor indices in one coalesced load
            int idx = csr[base + (lane < cnt ? lane : 0)];
            for (int j = 0; j < cnt; j += 8) {
                float s = 0.f;
#pragma unroll
                for (int u = 0; u < 8; ++u) {
                    int jc = (j + u < cnt) ? (j + u) : (cnt - 1);   // uniform clamp
                    float a = x[(size_t)rli(idx, jc) * 64 + lane];  // 8 indep loads
                    s += (j + u < cnt) ? a : 0.f;
                }
                acc += s;
            }
        }
        agg[(size_t)node * 64 + lane] = acc;
    }
}

// ---------------- GEMM1 + BN + ReLU + GEMM2 + ReLU, in-place ----------------

__global__ __launch_bounds__(256, 2) void k_gemm(
    float* __restrict__ xb,                       // in: agg, out: layer output
    const float* __restrict__ Wt1, const float* __restrict__ b1,
    const float* __restrict__ gamma, const float* __restrict__ beta,
    const float* __restrict__ mean, const float* __restrict__ var,
    const float* __restrict__ Wt2, const float* __restrict__ b2, int n)
{
    int lane = threadIdx.x & 63;
    int wid = (blockIdx.x * blockDim.x + threadIdx.x) >> 6;
    int nw = (gridDim.x * blockDim.x) >> 6;

    // lane's output column of W1/W2: 16+16 contiguous float4 loads
    float4 w1v[16], w2v[16];
    const float4* W1p = (const float4*)Wt1 + (size_t)lane * 16;
    const float4* W2p = (const float4*)Wt2 + (size_t)lane * 16;
#pragma unroll
    for (int q = 0; q < 16; ++q) w1v[q] = W1p[q];
#pragma unroll
    for (int q = 0; q < 16; ++q) w2v[q] = W2p[q];
    // pin in VGPRs: values become opaque, compiler cannot re-sink the loads
#pragma unroll
    for (int q = 0; q < 16; ++q) {
        asm volatile("" : "+v"(w1v[q].x), "+v"(w1v[q].y), "+v"(w1v[q].z), "+v"(w1v[q].w));
        asm volatile("" : "+v"(w2v[q].x), "+v"(w2v[q].y), "+v"(w2v[q].z), "+v"(w2v[q].w));
    }
    const float* w1 = (const float*)w1v;
    const float* w2 = (const float*)w2v;

    float bias1 = b1[lane];
    float sc = gamma[lane] * rsqrtf(var[lane] + 1e-5f);
    float sh = beta[lane] - mean[lane] * sc;
    float bias2 = b2[lane];

    for (int node = wid; node < n; node += nw) {
        float a = xb[(size_t)node * 64 + lane];
        float h0 = bias1, h1 = 0.f;
#pragma unroll
        for (int k = 0; k < 64; k += 2) {            // 2 chains for FMA-latency ILP
            h0 += rlf(a, k)     * w1[k];
            h1 += rlf(a, k + 1) * w1[k + 1];
        }
        float h = fmaxf((h0 + h1) * sc + sh, 0.f);
        float o0 = bias2, o1 = 0.f;
#pragma unroll
        for (int k = 0; k < 64; k += 2) {
            o0 += rlf(h, k)     * w2[k];
            o1 += rlf(h, k + 1) * w2[k + 1];
        }
        xb[(size_t)node * 64 + lane] = fmaxf(o0 + o1, 0.f);
    }
}

// ---------------- per-graph pooling ----------------

__global__ __launch_bounds__(256) void k_pool(const float* __restrict__ x,
                                              const int* __restrict__ gs,
                                              float* __restrict__ pooled,
                                              int G, int l, int lh) {
    int lane = threadIdx.x & 63;
    int wid = (blockIdx.x * blockDim.x + threadIdx.x) >> 6;
    if (wid >= G) return;
    int s0 = gs[wid], s1 = gs[wid + 1];
    float a0 = 0, a1 = 0, a2 = 0, a3 = 0;
    int nd = s0;
    for (; nd + 4 <= s1; nd += 4) {
        a0 += x[(size_t)(nd + 0) * 64 + lane];
        a1 += x[(size_t)(nd + 1) * 64 + lane];
        a2 += x[(size_t)(nd + 2) * 64 + lane];
        a3 += x[(size_t)(nd + 3) * 64 + lane];
    }
    for (; nd < s1; ++nd) a0 += x[(size_t)nd * 64 + lane];
    pooled[(size_t)wid * lh + l * 64 + lane] = (a0 + a1) + (a2 + a3);
}

// ---------------- FC head ----------------

__global__ __launch_bounds__(256) void k_fc(
    const float* __restrict__ pooled, const int* __restrict__ acid,
    const float* __restrict__ conc, const float* __restrict__ emb_acid,
    const float* __restrict__ emb_conc, const float* __restrict__ fc1W,
    const float* __restrict__ fc1b, const float* __restrict__ fc2W,
    const float* __restrict__ fc2b, float* __restrict__ out, int G, int lh)
{
    __shared__ float sf[4][448];
    int lane = threadIdx.x & 63;
    int w = threadIdx.x >> 6;
    int g = blockIdx.x * 4 + w;
    int fcin = lh + 256;
    if (g < G) {
        const float* pr = pooled + (size_t)g * lh;
        for (int c = lane; c < lh; c += 64) sf[w][c] = pr[c];
        const float* ea = emb_acid + acid[g] * 128;
        int ci = (conc[g] == 0.5f) ? 0 : 1;
        const float* ec = emb_conc + ci * 128;
        sf[w][lh + lane] = ea[lane];
        sf[w][lh + 64 + lane] = ea[lane + 64];
        sf[w][lh + 128 + lane] = ec[lane];
        sf[w][lh + 192 + lane] = ec[lane + 64];
    }
    __syncthreads();
    if (g >= G) return;
    float h0 = fc1b[lane], h1 = 0.f;
    for (int k = 0; k + 2 <= fcin; k += 2) {
        h0 += sf[w][k] * fc1W[(size_t)k * 64 + lane];
        h1 += sf[w][k + 1] * fc1W[(size_t)(k + 1) * 64 + lane];
    }
    float h = fmaxf(h0 + h1, 0.f);
    float p0 = h * fc2W[lane * 2 + 0];
    float p1 = h * fc2W[lane * 2 + 1];
    for (int off = 32; off; off >>= 1) {
        p0 += __shfl_xor(p0, off, 64);
        p1 += __shfl_xor(p1, off, 64);
    }
    if (lane == 0) {
        out[g * 2 + 0] = 1.0f / (1.0f + expf(-(p0 + fc2b[0])));
        out[g * 2 + 1] = 1.0f / (1.0f + expf(-(p1 + fc2b[1])));
    }
}

// ---------------- launch ----------------

extern "C" void kernel_launch(void* const* d_in, const int* in_sizes, int n_in,
                              void* d_out, int out_size, void* d_ws, size_t ws_size,
                              hipStream_t stream)
{
    const float* x_a      = (const float*)d_in[0];
    const int*   ei       = (const int*)d_in[1];
    const int*   batch    = (const int*)d_in[2];
    const int*   acid     = (const int*)d_in[3];
    const float* conc     = (const float*)d_in[4];
    const float* W1s      = (const float*)d_in[6];
    const float* b1s      = (const float*)d_in[7];
    const float* gammas   = (const float*)d_in[8];
    const float* betas    = (const float*)d_in[9];
    const float* bn_means = (const float*)d_in[10];
    const float* bn_vars  = (const float*)d_in[11];
    const float* W2s      = (const float*)d_in[12];
    const float* b2s      = (const float*)d_in[13];
    const float* emb_acid = (const float*)d_in[14];
    const float* emb_conc = (const float*)d_in[15];
    const float* fc1W     = (const float*)d_in[16];
    const float* fc1b     = (const float*)d_in[17];
    const float* fc2W     = (const float*)d_in[18];
    const float* fc2b     = (const float*)d_in[19];

    const int N = in_sizes[0] / 64;
    const int E = in_sizes[1] / 2;
    const int G = in_sizes[3];
    const int L = in_sizes[6] / (64 * 64);
    const int LH = 64 * L;

    char* ws = (char*)d_ws;
    size_t off = 0;
    auto alloc = [&](size_t bytes) -> void* {
        void* p = ws + off;
        off += (bytes + 255) & ~(size_t)255;
        return p;
    };
    float* buf0      = (float*)alloc((size_t)N * 64 * 4);
    float* buf1      = (float*)alloc((size_t)N * 64 * 4);
    float* pooled    = (float*)alloc((size_t)G * LH * 4);
    int*   row_start = (int*)alloc((size_t)(N + 1) * 4);
    int*   deg       = (int*)alloc((size_t)N * 4);      // reused as cursor
    int*   csr       = (int*)alloc((size_t)E * 4);
    int*   bsum      = (int*)alloc(4096);
    int*   gs        = (int*)alloc((size_t)(G + 1) * 4);
    float* Wt1       = (float*)alloc((size_t)L * 4096 * 4);
    float* Wt2       = (float*)alloc((size_t)L * 4096 * 4);

    const int* srcv = ei;
    const int* dstv = ei + E;

    // CSR build (reused by all layers)
    hipMemsetAsync(deg, 0, (size_t)N * 4, stream);
    k_hist<<<4096, 256, 0, stream>>>(dstv, deg, E);
    int nb = (N + SCAN_B - 1) / SCAN_B;
    k_scan1<<<nb, SCAN_B, 0, stream>>>(deg, row_start, bsum, N);
    k_scan2<<<1, SCAN_B, 0, stream>>>(bsum, nb);
    k_scan3<<<nb, SCAN_B, 0, stream>>>(row_start, bsum, N, E);
    hipMemsetAsync(deg, 0, (size_t)N * 4, stream);
    k_scatter<<<4096, 256, 0, stream>>>(srcv, dstv, row_start, deg, csr, E);
    k_gstart<<<(G + 256) / 256, 256, 0, stream>>>(batch, gs, N, G);

    // weight transposes (lane-major columns)
    int wtot = L * 4096;
    k_wt<<<(wtot + 255) / 256, 256, 0, stream>>>(W1s, Wt1, wtot);
    k_wt<<<(wtot + 255) / 256, 256, 0, stream>>>(W2s, Wt2, wtot);

    // GIN layers: gather -> in-place fused MLP -> pool
    const float* xin = x_a;
    float* bufs[2] = {buf0, buf1};
    for (int l = 0; l < L; ++l) {
        float* xb = bufs[l & 1];
        k_gather<<<4096, 256, 0, stream>>>(xin, row_start, csr, xb, N);
        k_gemm<<<2048, 256, 0, stream>>>(
            xb, Wt1 + (size_t)l * 4096, b1s + l * 64,
            gammas + l * 64, betas + l * 64,
            bn_means + l * 64, bn_vars + l * 64,
            Wt2 + (size_t)l * 4096, b2s + l * 64, N);
        k_pool<<<(G + 3) / 4, 256, 0, stream>>>(xb, gs, pooled, G, l, LH);
        xin = xb;
    }

    // FC head
    k_fc<<<(G + 3) / 4, 256, 0, stream>>>(pooled, acid, conc, emb_acid, emb_conc,
                                          fc1W, fc1b, fc2W, fc2b,
                                          (float*)d_out, G, LH);
}